// Round 1
// baseline (3537.251 us; speedup 1.0000x reference)
//
#include <hip/hip_runtime.h>
#include <cmath>

// Problem constants
#define M_MOD 8
#define BATCH 4096
#define DIM   512
#define NPAIR 56            // M*(M-1)
#define KT    16
#define LDSP  68            // 64 + 4 pad, keeps 16B alignment (68*4=272, 272%16==0)

static const size_t BD = (size_t)BATCH * DIM;   // 2,097,152

// ---- d_out layout (float offsets), return order:
// fused (M,B,D), unified (B,D), attn_w (P,B,1), attended (P,B,D), importance (B,M), heatmap (M,M)
#define OFF_FUSED   0UL
#define OFF_UNIFIED 16777216UL
#define OFF_ATTNW   18874368UL
#define OFF_ATT     19103744UL
#define OFF_IMP     136544256UL
#define OFF_HEAT    136577024UL

// ---- workspace layout (float offsets). Total need = 35,684,352 floats = 142.8 MB
#define WS_CROSS 0UL          // M*B*D = 16,777,216
#define WS_T1    16777216UL   // B*D   =  2,097,152
#define WS_GACC  18874368UL   // M*B   =     32,768
#define WS_WC    18907136UL   // P*D*D = 14,680,064  (dead after k_att)
#define WS_BC    33587200UL   // P*D   =     28,672  (dead after k_att)
#define WS_H1    18907136UL   // M*B*D = 16,777,216  (overlaps WC+BC, which are dead by then)

// ---------------------------------------------------------------------------
// Core: C[row][col] = sum_k X[row][k] * W[col][k]   (NT GEMM, both K-contiguous)
// 64x64 tile, 256 threads, 4x4 per thread, KT=16 LDS staging (transposed).
// ---------------------------------------------------------------------------
__device__ __forceinline__ void gemm_nt_core(
    const float* __restrict__ X, int ldx,
    const float* __restrict__ W, int ldw,
    int K, int row0, int col0, float acc[4][4])
{
    __shared__ float Xs[KT][LDSP];
    __shared__ float Ws[KT][LDSP];
    const int tid  = threadIdx.x;
    const int lrow = tid >> 2;          // 0..63
    const int kq   = (tid & 3) << 2;    // 0,4,8,12
    const int ty   = tid >> 4;          // 0..15
    const int tx   = tid & 15;          // 0..15

#pragma unroll
    for (int i = 0; i < 4; ++i)
#pragma unroll
        for (int j = 0; j < 4; ++j) acc[i][j] = 0.f;

    const float* xrow = X + (size_t)(row0 + lrow) * ldx + kq;
    const float* wrow = W + (size_t)(col0 + lrow) * ldw + kq;

    for (int k0 = 0; k0 < K; k0 += KT) {
        float4 xv = *(const float4*)(xrow + k0);
        float4 wv = *(const float4*)(wrow + k0);
        __syncthreads();
        Xs[kq+0][lrow] = xv.x; Xs[kq+1][lrow] = xv.y;
        Xs[kq+2][lrow] = xv.z; Xs[kq+3][lrow] = xv.w;
        Ws[kq+0][lrow] = wv.x; Ws[kq+1][lrow] = wv.y;
        Ws[kq+2][lrow] = wv.z; Ws[kq+3][lrow] = wv.w;
        __syncthreads();
#pragma unroll
        for (int k = 0; k < KT; ++k) {
            float4 a4 = *(const float4*)&Xs[k][ty << 2];
            float4 b4 = *(const float4*)&Ws[k][tx << 2];
            float av[4] = {a4.x, a4.y, a4.z, a4.w};
            float bv[4] = {b4.x, b4.y, b4.z, b4.w};
#pragma unroll
            for (int i = 0; i < 4; ++i)
#pragma unroll
                for (int j = 0; j < 4; ++j)
                    acc[i][j] = fmaf(av[i], bv[j], acc[i][j]);
        }
    }
}

// ---------------------------------------------------------------------------
// Generic batched NT GEMM: C[z] = op( X[z] @ W[z]^T + bias[z] (+ C) )
// ---------------------------------------------------------------------------
template<bool ADD_C, bool RELU, bool HAS_BIAS>
__global__ __launch_bounds__(256)
void k_gemm_nt(const float* __restrict__ X, long long xz, int ldx,
               const float* __restrict__ W, long long wz, int ldw,
               const float* __restrict__ bias, long long bz,
               float* __restrict__ C, long long cz, int ldc, int K)
{
    const int z = blockIdx.z;
    const int row0 = blockIdx.y * 64, col0 = blockIdx.x * 64;
    float acc[4][4];
    gemm_nt_core(X + (size_t)z * xz, ldx, W + (size_t)z * wz, ldw, K, row0, col0, acc);

    const int ty = threadIdx.x >> 4, tx = threadIdx.x & 15;
    float bv[4] = {0.f, 0.f, 0.f, 0.f};
    if (HAS_BIAS) {
        const float* bp = bias + (size_t)z * bz + col0 + (tx << 2);
#pragma unroll
        for (int j = 0; j < 4; ++j) bv[j] = bp[j];
    }
#pragma unroll
    for (int i = 0; i < 4; ++i) {
        float* cp = C + (size_t)z * cz + (size_t)(row0 + (ty << 2) + i) * ldc + col0 + (tx << 2);
        float4 prev;
        if (ADD_C) prev = *(const float4*)cp;
        float v[4];
#pragma unroll
        for (int j = 0; j < 4; ++j) {
            float t = acc[i][j] + bv[j];
            if (ADD_C) t += ((const float*)&prev)[j];
            if (RELU)  t = fmaxf(t, 0.f);
            v[j] = t;
        }
        *(float4*)cp = make_float4(v[0], v[1], v[2], v[3]);
    }
}

// ---------------------------------------------------------------------------
// Wc[p] = Wo[p] @ Wv[p]   (NN GEMM, D x D x D per pair)
// Wo[e][f] = out_proj_w[p,e,f]; Wv[f][d] = in_proj_w[p, 2D+f, d]
// ---------------------------------------------------------------------------
__global__ __launch_bounds__(256)
void k_wc(const float* __restrict__ opw, const float* __restrict__ ipw,
          float* __restrict__ Wc)
{
    const int p = blockIdx.z;
    const float* A  = opw + (size_t)p * DIM * DIM;                       // [e][f]
    const float* Bm = ipw + (size_t)p * 3 * DIM * DIM + (size_t)2 * DIM * DIM; // [f][d]
    float* C = Wc + (size_t)p * DIM * DIM;

    __shared__ float As[KT][LDSP];   // As[f][e]
    __shared__ float Bs[KT][LDSP];   // Bs[f][d]
    const int tid  = threadIdx.x;
    const int lrow = tid >> 2, kq = (tid & 3) << 2;   // A load
    const int frow = tid >> 4, dq = (tid & 15) << 2;  // B load
    const int ty = tid >> 4, tx = tid & 15;
    const int e0 = blockIdx.y * 64, d0 = blockIdx.x * 64;

    float acc[4][4];
#pragma unroll
    for (int i = 0; i < 4; ++i)
#pragma unroll
        for (int j = 0; j < 4; ++j) acc[i][j] = 0.f;

    for (int k0 = 0; k0 < DIM; k0 += KT) {
        float4 av = *(const float4*)(A  + (size_t)(e0 + lrow) * DIM + k0 + kq);
        float4 bb = *(const float4*)(Bm + (size_t)(k0 + frow) * DIM + d0 + dq);
        __syncthreads();
        As[kq+0][lrow] = av.x; As[kq+1][lrow] = av.y;
        As[kq+2][lrow] = av.z; As[kq+3][lrow] = av.w;
        *(float4*)&Bs[frow][dq] = bb;
        __syncthreads();
#pragma unroll
        for (int k = 0; k < KT; ++k) {
            float4 a4 = *(const float4*)&As[k][ty << 2];
            float4 b4 = *(const float4*)&Bs[k][tx << 2];
            float avv[4] = {a4.x, a4.y, a4.z, a4.w};
            float bvv[4] = {b4.x, b4.y, b4.z, b4.w};
#pragma unroll
            for (int i = 0; i < 4; ++i)
#pragma unroll
                for (int j = 0; j < 4; ++j)
                    acc[i][j] = fmaf(avv[i], bvv[j], acc[i][j]);
        }
    }
#pragma unroll
    for (int i = 0; i < 4; ++i) {
        float* cp = C + (size_t)(e0 + (ty << 2) + i) * DIM + d0 + (tx << 2);
        *(float4*)cp = make_float4(acc[i][0], acc[i][1], acc[i][2], acc[i][3]);
    }
}

// bc[p][e] = sum_f Wo[p][e][f] * bv[p][f] + bo[p][e]
__global__ void k_bc(const float* __restrict__ opw, const float* __restrict__ ipb,
                     const float* __restrict__ opb, float* __restrict__ bc)
{
    const int p = blockIdx.x;
    const float4* bvp = (const float4*)(ipb + (size_t)p * 3 * DIM + 2 * DIM);
    for (int e = threadIdx.x; e < DIM; e += 256) {
        const float4* row = (const float4*)(opw + (size_t)p * DIM * DIM + (size_t)e * DIM);
        float s = 0.f;
        for (int f = 0; f < DIM / 4; ++f) {
            float4 a = row[f], b = bvp[f];
            s += a.x*b.x + a.y*b.y + a.z*b.z + a.w*b.w;
        }
        bc[(size_t)p * DIM + e] = s + opb[(size_t)p * DIM + e];
    }
}

// attended[p] = modal_embs[tgt(p)] @ Wc[p]^T + bc[p]
__global__ __launch_bounds__(256)
void k_att(const float* __restrict__ me, const float* __restrict__ Wc,
           const float* __restrict__ bc, float* __restrict__ att)
{
    const int p = blockIdx.z;
    const int m = p / 7, jj = p % 7;
    const int tgt = jj + (jj >= m ? 1 : 0);
    const int row0 = blockIdx.y * 64, col0 = blockIdx.x * 64;
    float acc[4][4];
    gemm_nt_core(me + (size_t)tgt * BD, DIM, Wc + (size_t)p * DIM * DIM, DIM, DIM, row0, col0, acc);

    const int ty = threadIdx.x >> 4, tx = threadIdx.x & 15;
    float bv[4];
    const float* bp = bc + (size_t)p * DIM + col0 + (tx << 2);
#pragma unroll
    for (int j = 0; j < 4; ++j) bv[j] = bp[j];
#pragma unroll
    for (int i = 0; i < 4; ++i) {
        float* cp = att + (size_t)p * BD + (size_t)(row0 + (ty << 2) + i) * DIM + col0 + (tx << 2);
        *(float4*)cp = make_float4(acc[i][0]+bv[0], acc[i][1]+bv[1], acc[i][2]+bv[2], acc[i][3]+bv[3]);
    }
}

// cross[m] = mean_j attended[m*7+j]
__global__ void k_cross(const float* __restrict__ att, float* __restrict__ cross)
{
    const size_t idx = (size_t)blockIdx.x * 256 + threadIdx.x;   // < M*B*D/4
    const int m = (int)(idx >> 19);
    const size_t r = idx & ((1UL << 19) - 1);
    const float4* a = (const float4*)att;
    float4 s = make_float4(0.f, 0.f, 0.f, 0.f);
#pragma unroll
    for (int j = 0; j < 7; ++j) {
        float4 v = a[(size_t)(m * 7 + j) * (BD / 4) + r];
        s.x += v.x; s.y += v.y; s.z += v.z; s.w += v.w;
    }
    const float c = 1.f / 7.f;
    ((float4*)cross)[idx] = make_float4(s.x*c, s.y*c, s.z*c, s.w*c);
}

// h2 partial-gate: gacc[m][b] += sum_e relu(fused@W^T + t1)[b][e] * w2[e]
__global__ __launch_bounds__(256)
void k_h2gate(const float* __restrict__ fused, const float* __restrict__ c1w,
              const float* __restrict__ t1, const float* __restrict__ c2w,
              float* __restrict__ gacc)
{
    const int m = blockIdx.z;
    const int row0 = blockIdx.y * 64, col0 = blockIdx.x * 64;
    float acc[4][4];
    // W = ctrl1_w columns [D..2D): row stride 2D, offset +D
    gemm_nt_core(fused + (size_t)m * BD, DIM, c1w + DIM, 2 * DIM, DIM, row0, col0, acc);

    __shared__ float red[64][17];
    const int ty = threadIdx.x >> 4, tx = threadIdx.x & 15;
    float w2[4];
#pragma unroll
    for (int j = 0; j < 4; ++j) w2[j] = c2w[col0 + (tx << 2) + j];
#pragma unroll
    for (int i = 0; i < 4; ++i) {
        const float* tp = t1 + (size_t)(row0 + (ty << 2) + i) * DIM + col0 + (tx << 2);
        float s = 0.f;
#pragma unroll
        for (int j = 0; j < 4; ++j) {
            float h = fmaxf(acc[i][j] + tp[j], 0.f);
            s = fmaf(h, w2[j], s);
        }
        red[(ty << 2) + i][tx] = s;
    }
    __syncthreads();
    if (threadIdx.x < 64) {
        float s = 0.f;
#pragma unroll
        for (int t = 0; t < 16; ++t) s += red[threadIdx.x][t];
        atomicAdd(gacc + (size_t)m * BATCH + row0 + threadIdx.x, s);
    }
}

// unified[b][d] = (1/M) * sum_m fused[m][b][d] * sigmoid(gacc[m][b] + c2b)
__global__ void k_unified(const float* __restrict__ fused, const float* __restrict__ gacc,
                          const float* __restrict__ c2b, float* __restrict__ uni)
{
    const size_t idx = (size_t)blockIdx.x * 256 + threadIdx.x;   // < B*D/4
    const int b = (int)(idx >> 7);
    const float cb = c2b[0];
    float4 s = make_float4(0.f, 0.f, 0.f, 0.f);
#pragma unroll
    for (int m = 0; m < M_MOD; ++m) {
        float g = 1.f / (1.f + expf(-(gacc[(size_t)m * BATCH + b] + cb)));
        float4 f = ((const float4*)fused)[(size_t)m * (BD / 4) + idx];
        s.x = fmaf(f.x, g, s.x); s.y = fmaf(f.y, g, s.y);
        s.z = fmaf(f.z, g, s.z); s.w = fmaf(f.w, g, s.w);
    }
    const float c = 1.f / (float)M_MOD;
    ((float4*)uni)[idx] = make_float4(s.x*c, s.y*c, s.z*c, s.w*c);
}

// attn_w = 1 everywhere; heatmap = 1 - I
__global__ void k_fill(float* __restrict__ out)
{
    const size_t gid = (size_t)blockIdx.x * 256 + threadIdx.x;
    if (gid < 229376UL) {
        out[OFF_ATTNW + gid] = 1.0f;
    } else if (gid < 229440UL) {
        const int r8 = (int)(gid - 229376UL);
        out[OFF_HEAT + r8] = ((r8 >> 3) == (r8 & 7)) ? 0.f : 1.f;
    }
}

// importance[b][m] = ||modal_embs[m,b,:]||
__global__ void k_imp(const float* __restrict__ me, float* __restrict__ imp)
{
    const int idx = blockIdx.x * 256 + threadIdx.x;   // < B*M
    const int b = idx >> 3, m = idx & 7;
    const float4* row = (const float4*)(me + (size_t)m * BD + (size_t)b * DIM);
    float s = 0.f;
    for (int i = 0; i < DIM / 4; ++i) {
        float4 v = row[i];
        s += v.x*v.x + v.y*v.y + v.z*v.z + v.w*v.w;
    }
    imp[idx] = sqrtf(s);
}

// ---------------------------------------------------------------------------
extern "C" void kernel_launch(void* const* d_in, const int* in_sizes, int n_in,
                              void* d_out, int out_size, void* d_ws, size_t ws_size,
                              hipStream_t stream)
{
    const float* me  = (const float*)d_in[0];
    const float* rq  = (const float*)d_in[1];
    const float* ipw = (const float*)d_in[2];
    const float* ipb = (const float*)d_in[3];
    const float* opw = (const float*)d_in[4];
    const float* opb = (const float*)d_in[5];
    const float* f1w = (const float*)d_in[6];
    const float* f1b = (const float*)d_in[7];
    const float* f2w = (const float*)d_in[8];
    const float* f2b = (const float*)d_in[9];
    const float* c1w = (const float*)d_in[10];
    const float* c1b = (const float*)d_in[11];
    const float* c2w = (const float*)d_in[12];
    const float* c2b = (const float*)d_in[13];
    float* out = (float*)d_out;
    float* ws  = (float*)d_ws;   // needs >= 142.8 MB

    float* wsCross = ws + WS_CROSS;
    float* wsT1    = ws + WS_T1;
    float* wsGacc  = ws + WS_GACC;
    float* wsWc    = ws + WS_WC;
    float* wsBc    = ws + WS_BC;
    float* wsH1    = ws + WS_H1;

    dim3 blk(256);

    // 1. Wc[p] = Wo[p] @ Wv[p]
    k_wc<<<dim3(8, 8, NPAIR), blk, 0, stream>>>(opw, ipw, wsWc);
    // 2. bc[p] = Wo[p] @ bv[p] + bo[p]
    k_bc<<<dim3(NPAIR), blk, 0, stream>>>(opw, ipb, opb, wsBc);
    // 3. attended (q,k dead: attn==1 -> ctx==v -> fold Wv into Wo)
    k_att<<<dim3(8, 64, NPAIR), blk, 0, stream>>>(me, wsWc, wsBc, out + OFF_ATT);
    // 4. cross = mean over the 7 targets
    k_cross<<<dim3(16384), blk, 0, stream>>>(out + OFF_ATT, wsCross);
    // 5. h1 pass A: modal_embs @ fus1_w[:, :D]^T + b1
    k_gemm_nt<false, false, true><<<dim3(8, 64, M_MOD), blk, 0, stream>>>(
        me, (long long)BD, DIM, f1w, (long long)DIM * 2 * DIM, 2 * DIM,
        f1b, DIM, wsH1, (long long)BD, DIM, DIM);
    // 6. h1 pass B: += cross @ fus1_w[:, D:]^T, relu
    k_gemm_nt<true, true, false><<<dim3(8, 64, M_MOD), blk, 0, stream>>>(
        wsCross, (long long)BD, DIM, f1w + DIM, (long long)DIM * 2 * DIM, 2 * DIM,
        nullptr, 0, wsH1, (long long)BD, DIM, DIM);
    // 7. fused = h1 @ fus2_w^T + b2  -> d_out
    k_gemm_nt<false, false, true><<<dim3(8, 64, M_MOD), blk, 0, stream>>>(
        wsH1, (long long)BD, DIM, f2w, (long long)DIM * DIM, DIM,
        f2b, DIM, out + OFF_FUSED, (long long)BD, DIM, DIM);
    // 8. zero gate accumulator
    hipMemsetAsync(wsGacc, 0, (size_t)M_MOD * BATCH * sizeof(float), stream);
    // 9. t1 = rq @ ctrl1_w[:, :D]^T + c1b  (shared across all m)
    k_gemm_nt<false, false, true><<<dim3(8, 64, 1), blk, 0, stream>>>(
        rq, 0LL, DIM, c1w, 0LL, 2 * DIM, c1b, 0LL, wsT1, 0LL, DIM, DIM);
    // 10. gate partials: relu(t1 + fused@ctrl1_w[:,D:]^T) . ctrl2_w
    k_h2gate<<<dim3(8, 64, M_MOD), blk, 0, stream>>>(out + OFF_FUSED, c1w, wsT1, c2w, wsGacc);
    // 11. unified
    k_unified<<<dim3(2048), blk, 0, stream>>>(out + OFF_FUSED, wsGacc, c2b, out + OFF_UNIFIED);
    // 12. attn_w (all ones) + heatmap (1 - I)
    k_fill<<<dim3(897), blk, 0, stream>>>(out);
    // 13. importance
    k_imp<<<dim3(128), blk, 0, stream>>>(me, out + OFF_IMP);
}

// Round 2
// 1328.319 us; speedup vs baseline: 2.6630x; 2.6630x over previous
//
#include <hip/hip_runtime.h>
#include <cmath>

// Problem constants
#define M_MOD 8
#define BATCH 4096
#define DIM   512
#define NPAIR 56
static const size_t BD = (size_t)BATCH * DIM;   // 2,097,152

typedef __attribute__((ext_vector_type(8))) short  short8;   // 8 bf16 = 4 VGPRs
typedef __attribute__((ext_vector_type(4))) float  floatx4;

// ---- d_out layout (float offsets)
#define OFF_FUSED   0UL
#define OFF_UNIFIED 16777216UL
#define OFF_ATTNW   18874368UL
#define OFF_ATT     19103744UL
#define OFF_IMP     136544256UL
#define OFF_HEAT    136577024UL

// ---- workspace layout (BYTE offsets). Total need = 181,649,408 B (~182 MB).
// comb_bf (M,B,1024) bf16: cols 0:512 = modal_embs, cols 512:1024 = cross
#define WB_COMB   0UL
// U1: phase1 = opw_bf(29.3MB)+wvT_bf(29.3MB); phase2 (after k_wc) = h1_bf+fused_bf
#define WB_U1     67108864UL
#define WB_OPW    (WB_U1)
#define WB_WVT    (WB_U1 + 29360128UL)
#define WB_H1     (WB_U1)
#define WB_FUSEDB (WB_U1 + 33554432UL)
// U2: Wc_bf (29.3MB); after k_att reused for t1 (8.4MB fp32)
#define WB_U2     134217728UL
// U3: small persistents
#define WB_F1W    163577856UL
#define WB_F2W    (WB_F1W + 8388608UL)
#define WB_C1W    (WB_F2W + 4194304UL)
#define WB_RQ     (WB_C1W + 1048576UL)
#define WB_GACC   (WB_RQ  + 4194304UL)
#define WB_BC     (WB_GACC + 131072UL)

// ---------------------------------------------------------------------------
__device__ __forceinline__ unsigned short f2b_bits(float f) {
    unsigned int u = __float_as_uint(f);
    unsigned int r = (u + 0x7fffu + ((u >> 16) & 1u)) >> 16;   // RNE
    return (unsigned short)r;
}

__device__ __forceinline__ void gload16(const unsigned short* g, short* l) {
    __builtin_amdgcn_global_load_lds((const __attribute__((address_space(1))) void*)g,
                                     (__attribute__((address_space(3))) void*)l,
                                     16, 0, 0);
}

// ---------------------------------------------------------------------------
// bf16 MFMA NT GEMM: C[z][i][j] = sum_k A[z][i][k] * B[z][j][k]
// 128x128 tile, 4 waves (2x2), each wave 4x4 of 16x16x32 MFMA, BK=32.
// EPI: 0 = bf16 out (no bias)         [Wc]
//      1 = fp32 out + bias            [attended, t1]
//      2 = relu(acc+bias) -> bf16     [h1]
//      3 = acc+bias -> fp32 AND bf16  [fused]
//      4 = gate reduction -> atomicAdd gacc   [h2/gate]
// TGT: A batch index = tgt(pair z) instead of z.
// ---------------------------------------------------------------------------
template<int EPI, bool TGT>
__global__ __launch_bounds__(256)
void k_mm(const unsigned short* __restrict__ A, long long az, int lda,
          const unsigned short* __restrict__ B, long long bz, int ldb,
          const float* __restrict__ bias, int biasz,
          float* __restrict__ Cf, long long cfz,
          unsigned short* __restrict__ Cb, long long cbz,
          const float* __restrict__ t1, const float* __restrict__ c2w,
          float* __restrict__ gacc, int K)
{
    const int z = blockIdx.z;
    int za = z;
    if (TGT) { int m = z / 7, j = z % 7; za = j + (j >= m ? 1 : 0); }
    const unsigned short* Ab = A + (size_t)za * az;
    const unsigned short* Bb = B + (size_t)z * bz;
    const int row0 = blockIdx.y * 128, col0 = blockIdx.x * 128;

    __shared__ short As[128 * 32];   // [row][k], 64 B per row
    __shared__ short Bs[128 * 32];   // [col][k]

    const int tid = threadIdx.x, w = tid >> 6, lane = tid & 63;
    // staging: wave w fills rows 32w..32w+31 of As and Bs (two 16-row chunks)
    const int srow = 32 * w + (lane >> 2);
    const int skq  = (lane & 3) * 8;
    const unsigned short* ga = Ab + (size_t)(row0 + srow) * lda + skq;
    const unsigned short* gb = Bb + (size_t)(col0 + srow) * ldb + skq;
    short* lA = As + 1024 * w;
    short* lB = Bs + 1024 * w;

    const int tg = lane >> 4, tm = lane & 15;          // frag indices
    const int wr = (w >> 1) * 64, wc = (w & 1) * 64;   // wave tile origin

    floatx4 acc[4][4];
    const floatx4 zero4 = {0.f, 0.f, 0.f, 0.f};
#pragma unroll
    for (int i = 0; i < 4; ++i)
#pragma unroll
        for (int j = 0; j < 4; ++j) acc[i][j] = zero4;

    for (int k0 = 0; k0 < K; k0 += 32) {
        gload16(ga + k0,                    lA);
        gload16(ga + k0 + (size_t)16 * lda, lA + 512);
        gload16(gb + k0,                    lB);
        gload16(gb + k0 + (size_t)16 * ldb, lB + 512);
        __syncthreads();   // drains own vmcnt before barrier
        short8 av[4], bv[4];
#pragma unroll
        for (int i = 0; i < 4; ++i)
            av[i] = *(const short8*)(As + (wr + i * 16 + tm) * 32 + tg * 8);
#pragma unroll
        for (int j = 0; j < 4; ++j)
            bv[j] = *(const short8*)(Bs + (wc + j * 16 + tm) * 32 + tg * 8);
#pragma unroll
        for (int i = 0; i < 4; ++i)
#pragma unroll
            for (int j = 0; j < 4; ++j)
                acc[i][j] = __builtin_amdgcn_mfma_f32_16x16x32_bf16(av[i], bv[j], acc[i][j], 0, 0, 0);
        __syncthreads();   // all waves done reading before next overwrite
    }

    // ---- epilogue. C/D layout: col = lane&15, row = (lane>>4)*4 + reg
    const int gc0 = col0 + wc + tm;
    const int gr0 = row0 + wr + tg * 4;

    if (EPI == 4) {
#pragma unroll
        for (int i = 0; i < 4; ++i)
#pragma unroll
            for (int reg = 0; reg < 4; ++reg) {
                const int r = gr0 + i * 16 + reg;
                float s = 0.f;
#pragma unroll
                for (int j = 0; j < 4; ++j) {
                    const int c = gc0 + j * 16;
                    float h = fmaxf(acc[i][j][reg] + t1[(size_t)r * DIM + c], 0.f);
                    s = fmaf(h, c2w[c], s);
                }
                s += __shfl_xor(s, 8); s += __shfl_xor(s, 4);
                s += __shfl_xor(s, 2); s += __shfl_xor(s, 1);
                if (tm == 0) atomicAdd(gacc + (size_t)z * BATCH + r, s);
            }
    } else {
        float bb[4] = {0.f, 0.f, 0.f, 0.f};
        if (EPI == 1 || EPI == 2 || EPI == 3) {
#pragma unroll
            for (int j = 0; j < 4; ++j) bb[j] = bias[(size_t)z * biasz + gc0 + j * 16];
        }
#pragma unroll
        for (int i = 0; i < 4; ++i)
#pragma unroll
            for (int reg = 0; reg < 4; ++reg) {
                const size_t rbase = (size_t)(gr0 + i * 16 + reg) * DIM;
#pragma unroll
                for (int j = 0; j < 4; ++j) {
                    const int c = gc0 + j * 16;
                    float v = acc[i][j][reg] + bb[j];
                    if (EPI == 2) v = fmaxf(v, 0.f);
                    if (EPI == 0 || EPI == 2 || EPI == 3)
                        Cb[(size_t)z * cbz + rbase + c] = f2b_bits(v);
                    if (EPI == 1 || EPI == 3)
                        Cf[(size_t)z * cfz + rbase + c] = v;
                }
            }
    }
}

// ---------------------------------------------------------------------------
// Conversion kernels
// ---------------------------------------------------------------------------
__global__ void k_f2b(const float* __restrict__ in, unsigned short* __restrict__ out, int n4)
{
    int i = blockIdx.x * 256 + threadIdx.x;
    if (i >= n4) return;
    float4 v = ((const float4*)in)[i];
    ushort4 o;
    o.x = f2b_bits(v.x); o.y = f2b_bits(v.y); o.z = f2b_bits(v.z); o.w = f2b_bits(v.w);
    *(ushort4*)(out + (size_t)i * 4) = o;
}

// modal_embs -> comb_bf cols 0:512 (ld 1024)
__global__ void k_me2comb(const float* __restrict__ me, unsigned short* __restrict__ comb)
{
    int gid = blockIdx.x * 256 + threadIdx.x;          // < M*B*128
    int row = gid >> 7;                                 // mb index
    int dq  = (gid & 127) * 4;
    float4 v = *(const float4*)(me + (size_t)row * 512 + dq);
    ushort4 o;
    o.x = f2b_bits(v.x); o.y = f2b_bits(v.y); o.z = f2b_bits(v.z); o.w = f2b_bits(v.w);
    *(ushort4*)(comb + (size_t)row * 1024 + dq) = o;
}

// Wv transpose-convert: wvT[p][d][f] = ipw[p][2D+f][d]
__global__ void k_wvT(const float* __restrict__ ipw, unsigned short* __restrict__ wvT)
{
    __shared__ float t[32][33];
    const int p = blockIdx.z;
    const float* src = ipw + (size_t)p * 3 * DIM * DIM + (size_t)2 * DIM * DIM;
    const int d0 = blockIdx.x * 32, f0 = blockIdx.y * 32;
    for (int r = threadIdx.y; r < 32; r += 8)
        t[r][threadIdx.x] = src[(size_t)(f0 + r) * DIM + d0 + threadIdx.x];
    __syncthreads();
    unsigned short* dst = wvT + (size_t)p * DIM * DIM;
    for (int r = threadIdx.y; r < 32; r += 8)
        dst[(size_t)(d0 + r) * DIM + f0 + threadIdx.x] = f2b_bits(t[threadIdx.x][r]);
}

// bc[p][e] = sum_f Wo[p][e][f]*bv[p][f] + bo[p][e]   (fp32, tiny)
__global__ void k_bc(const float* __restrict__ opw, const float* __restrict__ ipb,
                     const float* __restrict__ opb, float* __restrict__ bc)
{
    const int p = blockIdx.x;
    const float4* bvp = (const float4*)(ipb + (size_t)p * 3 * DIM + 2 * DIM);
    for (int e = threadIdx.x; e < DIM; e += 256) {
        const float4* row = (const float4*)(opw + (size_t)p * DIM * DIM + (size_t)e * DIM);
        float s = 0.f;
        for (int f = 0; f < DIM / 4; ++f) {
            float4 a = row[f], b = bvp[f];
            s += a.x * b.x + a.y * b.y + a.z * b.z + a.w * b.w;
        }
        bc[(size_t)p * DIM + e] = s + opb[(size_t)p * DIM + e];
    }
}

// cross = mean_j attended[m*7+j]; write bf16 into comb cols 512:1024
__global__ void k_cross(const float* __restrict__ att, unsigned short* __restrict__ comb)
{
    const int gid = blockIdx.x * 256 + threadIdx.x;    // < M*B*D/4 = 4,194,304
    const int m = gid >> 19;
    const int r = gid & ((1 << 19) - 1);
    const float4* a = (const float4*)att;
    float4 s = make_float4(0.f, 0.f, 0.f, 0.f);
#pragma unroll
    for (int j = 0; j < 7; ++j) {
        float4 v = a[(size_t)(m * 7 + j) * (BD / 4) + r];
        s.x += v.x; s.y += v.y; s.z += v.z; s.w += v.w;
    }
    const float c = 1.f / 7.f;
    const int row = r >> 7, dq = (r & 127) * 4;
    ushort4 o;
    o.x = f2b_bits(s.x * c); o.y = f2b_bits(s.y * c);
    o.z = f2b_bits(s.z * c); o.w = f2b_bits(s.w * c);
    *(ushort4*)(comb + ((size_t)(m * 4096 + row)) * 1024 + 512 + dq) = o;
}

// unified[b][d] = (1/M) * sum_m fused[m][b][d] * sigmoid(gacc[m][b] + c2b)
__global__ void k_unified(const float* __restrict__ fused, const float* __restrict__ gacc,
                          const float* __restrict__ c2b, float* __restrict__ uni)
{
    const size_t idx = (size_t)blockIdx.x * 256 + threadIdx.x;   // < B*D/4
    const int b = (int)(idx >> 7);
    const float cb = c2b[0];
    float4 s = make_float4(0.f, 0.f, 0.f, 0.f);
#pragma unroll
    for (int m = 0; m < M_MOD; ++m) {
        float g = 1.f / (1.f + expf(-(gacc[(size_t)m * BATCH + b] + cb)));
        float4 f = ((const float4*)fused)[(size_t)m * (BD / 4) + idx];
        s.x = fmaf(f.x, g, s.x); s.y = fmaf(f.y, g, s.y);
        s.z = fmaf(f.z, g, s.z); s.w = fmaf(f.w, g, s.w);
    }
    const float c = 1.f / (float)M_MOD;
    ((float4*)uni)[idx] = make_float4(s.x * c, s.y * c, s.z * c, s.w * c);
}

__global__ void k_fill(float* __restrict__ out)
{
    const size_t gid = (size_t)blockIdx.x * 256 + threadIdx.x;
    if (gid < 229376UL) {
        out[OFF_ATTNW + gid] = 1.0f;
    } else if (gid < 229440UL) {
        const int r8 = (int)(gid - 229376UL);
        out[OFF_HEAT + r8] = ((r8 >> 3) == (r8 & 7)) ? 0.f : 1.f;
    }
}

__global__ void k_imp(const float* __restrict__ me, float* __restrict__ imp)
{
    const int idx = blockIdx.x * 256 + threadIdx.x;    // < B*M
    const int b = idx >> 3, m = idx & 7;
    const float4* row = (const float4*)(me + (size_t)m * BD + (size_t)b * DIM);
    float s = 0.f;
    for (int i = 0; i < DIM / 4; ++i) {
        float4 v = row[i];
        s += v.x * v.x + v.y * v.y + v.z * v.z + v.w * v.w;
    }
    imp[idx] = sqrtf(s);
}

// ---------------------------------------------------------------------------
extern "C" void kernel_launch(void* const* d_in, const int* in_sizes, int n_in,
                              void* d_out, int out_size, void* d_ws, size_t ws_size,
                              hipStream_t stream)
{
    const float* me  = (const float*)d_in[0];
    const float* rq  = (const float*)d_in[1];
    const float* ipw = (const float*)d_in[2];
    const float* ipb = (const float*)d_in[3];
    const float* opw = (const float*)d_in[4];
    const float* opb = (const float*)d_in[5];
    const float* f1w = (const float*)d_in[6];
    const float* f1b = (const float*)d_in[7];
    const float* f2w = (const float*)d_in[8];
    const float* f2b = (const float*)d_in[9];
    const float* c1w = (const float*)d_in[10];
    const float* c1b = (const float*)d_in[11];
    const float* c2w = (const float*)d_in[12];
    const float* c2b = (const float*)d_in[13];
    float* out = (float*)d_out;
    char*  wsb = (char*)d_ws;   // needs >= 181,649,408 bytes

    unsigned short* comb   = (unsigned short*)(wsb + WB_COMB);
    unsigned short* opw_bf = (unsigned short*)(wsb + WB_OPW);
    unsigned short* wvT_bf = (unsigned short*)(wsb + WB_WVT);
    unsigned short* h1_bf  = (unsigned short*)(wsb + WB_H1);
    unsigned short* fus_bf = (unsigned short*)(wsb + WB_FUSEDB);
    unsigned short* wc_bf  = (unsigned short*)(wsb + WB_U2);
    float*          t1     = (float*)(wsb + WB_U2);
    unsigned short* f1w_bf = (unsigned short*)(wsb + WB_F1W);
    unsigned short* f2w_bf = (unsigned short*)(wsb + WB_F2W);
    unsigned short* c1w_bf = (unsigned short*)(wsb + WB_C1W);
    unsigned short* rq_bf  = (unsigned short*)(wsb + WB_RQ);
    float*          gacc   = (float*)(wsb + WB_GACC);
    float*          bc     = (float*)(wsb + WB_BC);

    dim3 blk(256);

    // ---- conversions
    k_f2b<<<dim3(14336), blk, 0, stream>>>(opw, opw_bf, 3670016);            // out_proj_w
    k_wvT<<<dim3(16, 16, NPAIR), dim3(32, 8), 0, stream>>>(ipw, wvT_bf);     // Wv^T
    k_f2b<<<dim3(4096),  blk, 0, stream>>>(f1w, f1w_bf, 1048576);
    k_f2b<<<dim3(2048),  blk, 0, stream>>>(f2w, f2w_bf, 524288);
    k_f2b<<<dim3(512),   blk, 0, stream>>>(c1w, c1w_bf, 131072);
    k_f2b<<<dim3(2048),  blk, 0, stream>>>(rq,  rq_bf,  524288);
    k_me2comb<<<dim3(16384), blk, 0, stream>>>(me, comb);
    k_bc<<<dim3(NPAIR), blk, 0, stream>>>(opw, ipb, opb, bc);
    hipMemsetAsync(gacc, 0, (size_t)M_MOD * BATCH * sizeof(float), stream);

    // ---- Wc[p] = Wo[p] @ Wv[p]   (bf16 out)
    k_mm<0, false><<<dim3(4, 4, NPAIR), blk, 0, stream>>>(
        opw_bf, (long long)DIM * DIM, DIM, wvT_bf, (long long)DIM * DIM, DIM,
        nullptr, 0, nullptr, 0, wc_bf, (long long)DIM * DIM,
        nullptr, nullptr, nullptr, DIM);

    // ---- attended[p] = me[tgt(p)] @ Wc[p]^T + bc  (fp32 to d_out)
    k_mm<1, true><<<dim3(4, 32, NPAIR), blk, 0, stream>>>(
        comb, (long long)BATCH * 1024, 1024, wc_bf, (long long)DIM * DIM, DIM,
        bc, DIM, out + OFF_ATT, (long long)BD, nullptr, 0,
        nullptr, nullptr, nullptr, DIM);

    // ---- t1 = rq @ c1w[:, :D]^T + c1b  (fp32; overlays dead Wc region)
    k_mm<1, false><<<dim3(4, 32, 1), blk, 0, stream>>>(
        rq_bf, 0, DIM, c1w_bf, 0, 1024,
        c1b, 0, t1, 0, nullptr, 0,
        nullptr, nullptr, nullptr, DIM);

    // ---- cross = mean -> comb cols 512:1024 (bf16)
    k_cross<<<dim3(16384), blk, 0, stream>>>(out + OFF_ATT, comb);

    // ---- h1 = relu(comb @ f1w^T + f1b)  (K=1024, bf16 out)
    k_mm<2, false><<<dim3(4, 32, M_MOD), blk, 0, stream>>>(
        comb, (long long)BATCH * 1024, 1024, f1w_bf, (long long)DIM * 1024, 1024,
        f1b, DIM, nullptr, 0, h1_bf, (long long)BD,
        nullptr, nullptr, nullptr, 1024);

    // ---- fused = h1 @ f2w^T + f2b  (fp32 to d_out + bf16 copy)
    k_mm<3, false><<<dim3(4, 32, M_MOD), blk, 0, stream>>>(
        h1_bf, (long long)BD, DIM, f2w_bf, (long long)DIM * DIM, DIM,
        f2b, DIM, out + OFF_FUSED, (long long)BD, fus_bf, (long long)BD,
        nullptr, nullptr, nullptr, DIM);

    // ---- gate: gacc += sum_e relu(fused @ c1w[:,D:]^T + t1) * c2w
    k_mm<4, false><<<dim3(4, 32, M_MOD), blk, 0, stream>>>(
        fus_bf, (long long)BD, DIM, c1w_bf + 512, 0, 1024,
        nullptr, 0, nullptr, 0, nullptr, 0,
        t1, c2w, gacc, DIM);

    // ---- epilogue kernels
    k_unified<<<dim3(2048), blk, 0, stream>>>(out + OFF_FUSED, gacc, c2b, out + OFF_UNIFIED);
    k_fill<<<dim3(897), blk, 0, stream>>>(out);
    k_imp<<<dim3(128), blk, 0, stream>>>(me, out + OFF_IMP);
}